// Round 9
// baseline (601.478 us; speedup 1.0000x reference)
//
#include <hip/hip_runtime.h>

typedef unsigned short u16;
typedef __attribute__((ext_vector_type(4)))  float  f32x4;
typedef __attribute__((ext_vector_type(16))) float  f32x16;
typedef __attribute__((ext_vector_type(4)))  float  float4v;
typedef __attribute__((ext_vector_type(4)))  unsigned short u16x4;
typedef __attribute__((ext_vector_type(8)))  unsigned short u16x8;
typedef __attribute__((ext_vector_type(8)))  short s16x8;
typedef __attribute__((ext_vector_type(4)))  unsigned int u32x4;

#define SEQ 4096
#define DA  2048
#define NH  16
#define DKV 128

__device__ __forceinline__ u16 f2bf(float f) {
    unsigned u = __builtin_bit_cast(unsigned, f);
    u += 0x7FFFu + ((u >> 16) & 1u);           // round-nearest-even
    return (u16)(u >> 16);
}
__device__ __forceinline__ float bf2f(u16 h) {
    return __builtin_bit_cast(float, (unsigned)h << 16);
}
__device__ __forceinline__ f32x4 mfma16(u16x8 a, u16x8 b, f32x4 c) {
    return __builtin_amdgcn_mfma_f32_16x16x32_bf16(
        __builtin_bit_cast(s16x8, a), __builtin_bit_cast(s16x8, b), c, 0, 0, 0);
}
__device__ __forceinline__ f32x16 mfma32(u16x8 a, u16x8 b, f32x16 c) {
    return __builtin_amdgcn_mfma_f32_32x32x16_bf16(
        __builtin_bit_cast(s16x8, a), __builtin_bit_cast(s16x8, b), c, 0, 0, 0);
}
__device__ __forceinline__ unsigned cvtpk(float lo, float hi) {
    unsigned r;
    asm("v_cvt_pk_bf16_f32 %0, %1, %2" : "=v"(r) : "v"(lo), "v"(hi));
    return r;
}
// direct-to-LDS 16B load: per-lane global src, wave-uniform LDS base (+lane*16)
__device__ __forceinline__ void gld16(const u16* g, u16* l) {
    __builtin_amdgcn_global_load_lds(
        (const __attribute__((address_space(1))) unsigned int*)g,
        (__attribute__((address_space(3))) unsigned int*)l, 16, 0, 0);
}
// swizzled LDS addressing, 128B rows: XOR row&7 into byte-bit-4..6
__device__ __forceinline__ char* ldsp(void* base, int row, int bcol, int rowbytes) {
    int off = row * rowbytes + bcol;
    off ^= (row & 7) << 4;
    return (char*)base + off;
}
// swizzled LDS addressing, 256B rows: XOR row&15 into byte-bit-4..7
__device__ __forceinline__ char* ldsp256(void* base, int row, int bcol) {
    int off = row * 256 + bcol;
    off ^= (row & 15) << 4;
    return (char*)base + off;
}

// ---------------------------------------------------------------------------
// Transpose + split-convert: in f32 [B][R][C] -> oh/ol bf16 [B][C][R]
// ---------------------------------------------------------------------------
__global__ void transpose_split_k(const float* __restrict__ in, u16* __restrict__ oh,
                                  u16* __restrict__ ol, int R, int C) {
    __shared__ float tile[32][33];
    int b  = blockIdx.z;
    int r0 = blockIdx.x * 32, c0 = blockIdx.y * 32;
    const float* src = in + (size_t)b * R * C;
    int t = threadIdx.x;
    {
        int cl = t & 31, r = t >> 5;
        for (int i = 0; i < 4; ++i)
            tile[r + 8 * i][cl] = src[(size_t)(r0 + r + 8 * i) * C + (c0 + cl)];
    }
    __syncthreads();
    int rl = t & 31, c = t >> 5;
    size_t obase = (size_t)b * R * C;
    for (int i = 0; i < 4; ++i) {
        int cw = c + 8 * i;
        float x = tile[rl][cw];
        u16 h = f2bf(x);
        size_t o = obase + (size_t)(c0 + cw) * R + (r0 + rl);
        oh[o] = h;
        if (ol) ol[o] = f2bf(x - bf2f(h));
    }
}

// ---------------------------------------------------------------------------
// Projection GEMM with T14 async-stage (R6-proven).
// MODE 0: V -> bf16 transposed VT[h][v][s] (hi only). MODE 1: K split. MODE 2: Q split*1/128.
// ---------------------------------------------------------------------------
template <int MODE>
__global__ void __launch_bounds__(256, 2) proj_k(const float* __restrict__ A,
                                                 const u16* __restrict__ BTh,
                                                 const u16* __restrict__ BTl,
                                                 u16* __restrict__ Oh,
                                                 u16* __restrict__ Ol) {
    __shared__ u16 sAh[128 * 64];
    __shared__ u16 sBh[128 * 64];
    __shared__ u16 sAl[MODE ? 128 * 64 : 8];
    __shared__ u16 sBl[MODE ? 128 * 64 : 8];

    int t = threadIdx.x;
    int h = blockIdx.y;
    int bm0 = blockIdx.x * 128;
    int lane = t & 63, w = t >> 6, wr = w >> 1, wc = w & 1;
    int g = lane >> 4, c = lane & 15;

    f32x4 acc[4][4] = {};

    float4v pA[8];
    u16x8   pBh[4], pBl[4];

    auto prefetch = [&](int k0) {
#pragma unroll
        for (int i = 0; i < 8; ++i) {
            int idx = t + i * 256;
            int row = idx >> 4, c4 = idx & 15;
            pA[i] = *(const float4v*)(A + (size_t)(bm0 + row) * DA + k0 + c4 * 4);
        }
#pragma unroll
        for (int i = 0; i < 4; ++i) {
            int idx = t + i * 256;
            int row = idx >> 3, c8 = idx & 7;
            size_t gb = ((size_t)h * 128 + row) * DA + k0 + c8 * 8;
            pBh[i] = *(const u16x8*)(BTh + gb);
            if (MODE) pBl[i] = *(const u16x8*)(BTl + gb);
        }
    };
    auto write_lds = [&]() {
#pragma unroll
        for (int i = 0; i < 8; ++i) {
            int idx = t + i * 256;
            int row = idx >> 4, c4 = idx & 15;
            u16x4 hv, lv;
#pragma unroll
            for (int j = 0; j < 4; ++j) {
                u16 hh = f2bf(pA[i][j]);
                hv[j] = hh;
                lv[j] = f2bf(pA[i][j] - bf2f(hh));
            }
            *(u16x4*)ldsp(sAh, row, c4 * 8, 128) = hv;
            if (MODE) *(u16x4*)ldsp(sAl, row, c4 * 8, 128) = lv;
        }
#pragma unroll
        for (int i = 0; i < 4; ++i) {
            int idx = t + i * 256;
            int row = idx >> 3, c8 = idx & 7;
            *(u16x8*)ldsp(sBh, row, c8 * 16, 128) = pBh[i];
            if (MODE) *(u16x8*)ldsp(sBl, row, c8 * 16, 128) = pBl[i];
        }
    };

    prefetch(0);
    for (int k0 = 0; k0 < DA; k0 += 64) {
        __syncthreads();
        write_lds();
        __syncthreads();
        int nxt = (k0 + 64 < DA) ? k0 + 64 : 0;
        prefetch(nxt);

        for (int kc = 0; kc < 2; ++kc) {
            int kb = (kc * 32 + g * 8) * 2;
            u16x8 ah[4], al[4], bh[4], bl[4];
            for (int m = 0; m < 4; ++m) {
                int row = wr * 64 + m * 16 + c;
                ah[m] = *(u16x8*)ldsp(sAh, row, kb, 128);
                if (MODE) al[m] = *(u16x8*)ldsp(sAl, row, kb, 128);
            }
            for (int n = 0; n < 4; ++n) {
                int row = wc * 64 + n * 16 + c;
                bh[n] = *(u16x8*)ldsp(sBh, row, kb, 128);
                if (MODE) bl[n] = *(u16x8*)ldsp(sBl, row, kb, 128);
            }
            for (int m = 0; m < 4; ++m)
                for (int n = 0; n < 4; ++n) {
                    acc[m][n] = mfma16(ah[m], bh[n], acc[m][n]);
                    if (MODE) {
                        acc[m][n] = mfma16(ah[m], bl[n], acc[m][n]);
                        acc[m][n] = mfma16(al[m], bh[n], acc[m][n]);
                    }
                }
        }
    }

    const float scale = (MODE == 2) ? (1.0f / 128.0f) : 1.0f;
    for (int m = 0; m < 4; ++m)
        for (int n = 0; n < 4; ++n) {
            int col  = wc * 64 + n * 16 + c;
            int row0 = bm0 + wr * 64 + m * 16 + g * 4;
            if (MODE == 0) {
                u16x4 pv;
                for (int j = 0; j < 4; ++j) pv[j] = f2bf(acc[m][n][j]);
                *(u16x4*)(Oh + ((size_t)h * DKV + col) * SEQ + row0) = pv;
            } else {
                for (int j = 0; j < 4; ++j) {
                    float v = acc[m][n][j] * scale;
                    u16 hh = f2bf(v);
                    size_t o = ((size_t)h * SEQ + row0 + j) * DKV + col;
                    Oh[o] = hh;
                    Ol[o] = f2bf(v - bf2f(hh));
                }
            }
        }
}

// ---------------------------------------------------------------------------
// Flash attention (R6 structure, bf16-split, micro-optimized):
// - advancing stage pointers + per-thread constant offsets (no per-iter addr calc)
// - tree reductions for row-max and row-sum (break 4-cyc dep chains)
// - per-kt interleave of exp/pack/PV (exp(s[1]) hides under PV(kt=0) MFMAs)
// 8 waves x 32 q = 256 q/block, dbuf LDS 96KB, single barrier/iter,
// T13 defer-rescale, XCD-aware grid decode.
// ---------------------------------------------------------------------------
__global__ void __launch_bounds__(512, 1) attn_k(const u16* __restrict__ QH,
                                                 const u16* __restrict__ QL,
                                                 const u16* __restrict__ KH,
                                                 const u16* __restrict__ KL,
                                                 const u16* __restrict__ VT,
                                                 u16* __restrict__ Abuf) {
    __shared__ u16 sKh[2][64 * 128];
    __shared__ u16 sKl[2][64 * 128];
    __shared__ u16 sV [2][64 * 128];   // [64 rows][256B]: row r, half p = vdim p*64+r

    int t = threadIdx.x, lane = t & 63, w = t >> 6;   // w in 0..7
    int bid = blockIdx.x;
    int h  = (bid & 7) + 8 * ((bid >> 3) & 1);        // XCD x serves heads {x, x+8}
    int q0 = (bid >> 4) * 256;
    int c = lane & 31, hi = lane >> 5;
    int qrow = q0 + w * 32 + c;

    // Q fragments (B-operand layout): lane holds Q[qrow][dc*16 + hi*8 .. +7]
    u16x8 qh[8], ql[8];
    {
        size_t base = ((size_t)h * SEQ + qrow) * DKV + hi * 8;
#pragma unroll
        for (int dc = 0; dc < 8; ++dc) {
            qh[dc] = *(const u16x8*)(QH + base + dc * 16);
            ql[dc] = *(const u16x8*)(QL + base + dc * 16);
        }
    }

    f32x16 o[4] = {};
    float mrun = -3e38f, lrun = 0.f;

    // staging: advancing pointers + per-thread constant offsets
    const u16* khp = KH + (size_t)h * SEQ * DKV;
    const u16* klp = KL + (size_t)h * SEQ * DKV;
    const u16* vtp = VT + (size_t)h * DKV * SEQ;
    int ci0 = w * 2, ci1 = w * 2 + 1;                 // 1KB chunk indices (0..15)
    int rK0 = ci0 * 4 + (lane >> 4), rK1 = ci1 * 4 + (lane >> 4);
    int cK0 = (lane & 15) ^ (rK0 & 15), cK1 = (lane & 15) ^ (rK1 & 15);
    int kOff0 = rK0 * DKV + cK0 * 8, kOff1 = rK1 * DKV + cK1 * 8;
    int vOff0 = (((cK0 >> 3) << 6) + rK0) * SEQ + (cK0 & 7) * 8;
    int vOff1 = (((cK1 >> 3) << 6) + rK1) * SEQ + (cK1 & 7) * 8;
    int ld0 = ci0 * 512, ld1 = ci1 * 512;

    auto stage = [&](int b) {
        gld16(khp + kOff0, &sKh[b][ld0]);
        gld16(klp + kOff0, &sKl[b][ld0]);
        gld16(vtp + vOff0, &sV[b][ld0]);
        gld16(khp + kOff1, &sKh[b][ld1]);
        gld16(klp + kOff1, &sKl[b][ld1]);
        gld16(vtp + vOff1, &sV[b][ld1]);
        khp += 64 * DKV; klp += 64 * DKV; vtp += 64;
    };

    stage(0);
    const int NT = SEQ / 64;
    for (int it = 0; it < NT; ++it) {
        int b = it & 1;
        __syncthreads();               // drains stage loads, syncs all waves
        if (it + 1 < NT) stage(b ^ 1); // next tile in flight under compute

        // S^T = K * Q^T : s[kt] holds S[kv=(r&3)+8*(r>>2)+4*hi + 32*kt][q=c]
        f32x16 s[2] = {};
        __builtin_amdgcn_s_setprio(1);
#pragma unroll
        for (int kt = 0; kt < 2; ++kt) {
#pragma unroll
            for (int dc = 0; dc < 8; ++dc) {
                u16x8 kh = *(u16x8*)ldsp256(sKh[b], kt * 32 + c, dc * 32 + hi * 16);
                u16x8 kl = *(u16x8*)ldsp256(sKl[b], kt * 32 + c, dc * 32 + hi * 16);
                s[kt] = mfma32(kh, qh[dc], s[kt]);
                s[kt] = mfma32(kl, qh[dc], s[kt]);
                s[kt] = mfma32(kh, ql[dc], s[kt]);
            }
        }
        __builtin_amdgcn_s_setprio(0);

        // row max — tree reduce (break serial fmax chain)
        float tm[8];
#pragma unroll
        for (int i = 0; i < 8; ++i)
            tm[i] = fmaxf(fmaxf(s[0][2 * i], s[0][2 * i + 1]),
                          fmaxf(s[1][2 * i], s[1][2 * i + 1]));
        float vmax = fmaxf(fmaxf(fmaxf(tm[0], tm[1]), fmaxf(tm[2], tm[3])),
                           fmaxf(fmaxf(tm[4], tm[5]), fmaxf(tm[6], tm[7])));
        vmax = fmaxf(vmax, __shfl_xor(vmax, 32));

        // T13 defer-rescale (THR=8)
        if (!__all(vmax <= mrun + 8.0f)) {
            float mnew = fmaxf(mrun, vmax);
            float corr = __expf(mrun - mnew);
            mrun = mnew;
            lrun *= corr;
#pragma unroll
            for (int vt = 0; vt < 4; ++vt)
#pragma unroll
                for (int r = 0; r < 16; ++r) o[vt][r] *= corr;
        }

        // per-kt: exp (tree partial sums) -> pack -> PV; exp(s[1]) overlaps PV(kt=0)
        float rs = 0.f;
#pragma unroll
        for (int kt = 0; kt < 2; ++kt) {
            float r0 = 0.f, r1 = 0.f, r2 = 0.f, r3 = 0.f;
#pragma unroll
            for (int i = 0; i < 4; ++i) {
                float p0 = __expf(s[kt][4 * i + 0] - mrun);
                float p1 = __expf(s[kt][4 * i + 1] - mrun);
                float p2 = __expf(s[kt][4 * i + 2] - mrun);
                float p3 = __expf(s[kt][4 * i + 3] - mrun);
                s[kt][4 * i + 0] = p0; r0 += p0;
                s[kt][4 * i + 1] = p1; r1 += p1;
                s[kt][4 * i + 2] = p2; r2 += p2;
                s[kt][4 * i + 3] = p3; r3 += p3;
            }
            rs += (r0 + r1) + (r2 + r3);

            unsigned wv[8], xw[8];
#pragma unroll
            for (int i = 0; i < 8; ++i) wv[i] = cvtpk(s[kt][2 * i], s[kt][2 * i + 1]);
#pragma unroll
            for (int i = 0; i < 8; ++i) xw[i] = (unsigned)__shfl_xor((int)wv[i], 32);
            __builtin_amdgcn_s_setprio(1);
#pragma unroll
            for (int kc = 0; kc < 2; ++kc) {
                u32x4 pw;
                pw[0] = hi ? xw[4 * kc + 2] : wv[4 * kc + 0];
                pw[1] = hi ? xw[4 * kc + 3] : wv[4 * kc + 1];
                pw[2] = hi ? wv[4 * kc + 2] : xw[4 * kc + 0];
                pw[3] = hi ? wv[4 * kc + 3] : xw[4 * kc + 1];
                u16x8 pf = __builtin_bit_cast(u16x8, pw);
#pragma unroll
                for (int vt = 0; vt < 4; ++vt) {
                    int v = vt * 32 + c;
                    u16x8 vf = *(u16x8*)ldsp256(sV[b], v & 63,
                                                ((v >> 6) << 7) + kt * 64 + kc * 32 + hi * 16);
                    o[vt] = mfma32(vf, pf, o[vt]);
                }
            }
            __builtin_amdgcn_s_setprio(0);
        }
        rs += __shfl_xor(rs, 32);
        lrun += rs;
    }

    float inv = 1.0f / lrun;
#pragma unroll
    for (int vt = 0; vt < 4; ++vt)
#pragma unroll
        for (int rg = 0; rg < 4; ++rg) {
            u16x4 pv;
#pragma unroll
            for (int j = 0; j < 4; ++j) pv[j] = f2bf(o[vt][rg * 4 + j] * inv);
            *(u16x4*)(Abuf + (size_t)qrow * (NH * DKV) + h * DKV + vt * 32 + rg * 8 + hi * 4) = pv;
        }
}

// ---------------------------------------------------------------------------
// Final GEMM (T14, R6-proven): out f32 = Abuf bf16 @ W^T
// ---------------------------------------------------------------------------
__global__ void __launch_bounds__(256, 2) gemm_out_k(const u16* __restrict__ Abuf,
                                                     const u16* __restrict__ WT,
                                                     float* __restrict__ out) {
    __shared__ u16 sA[128 * 64];
    __shared__ u16 sB[128 * 64];
    int t = threadIdx.x, lane = t & 63, w = t >> 6, wr = w >> 1, wc = w & 1;
    int g = lane >> 4, c = lane & 15;
    int bm0 = blockIdx.x * 128, bn0 = blockIdx.y * 128;
    f32x4 acc[4][4] = {};

    u16x8 pA[4], pB[4];
    auto prefetch = [&](int k0) {
#pragma unroll
        for (int i = 0; i < 4; ++i) {
            int idx = t + i * 256, row = idx >> 3, c8 = idx & 7;
            pA[i] = *(const u16x8*)(Abuf + (size_t)(bm0 + row) * DA + k0 + c8 * 8);
            pB[i] = *(const u16x8*)(WT + (size_t)(bn0 + row) * DA + k0 + c8 * 8);
        }
    };
    auto write_lds = [&]() {
#pragma unroll
        for (int i = 0; i < 4; ++i) {
            int idx = t + i * 256, row = idx >> 3, c8 = idx & 7;
            *(u16x8*)ldsp(sA, row, c8 * 16, 128) = pA[i];
            *(u16x8*)ldsp(sB, row, c8 * 16, 128) = pB[i];
        }
    };

    prefetch(0);
    for (int k0 = 0; k0 < DA; k0 += 64) {
        __syncthreads();
        write_lds();
        __syncthreads();
        int nxt = (k0 + 64 < DA) ? k0 + 64 : 0;
        prefetch(nxt);

        for (int kc = 0; kc < 2; ++kc) {
            int kb = (kc * 32 + g * 8) * 2;
            u16x8 af[4], bfq[4];
            for (int m = 0; m < 4; ++m) af[m]  = *(u16x8*)ldsp(sA, wr * 64 + m * 16 + c, kb, 128);
            for (int n = 0; n < 4; ++n) bfq[n] = *(u16x8*)ldsp(sB, wc * 64 + n * 16 + c, kb, 128);
            for (int m = 0; m < 4; ++m)
                for (int n = 0; n < 4; ++n)
                    acc[m][n] = mfma16(af[m], bfq[n], acc[m][n]);
        }
    }
    for (int m = 0; m < 4; ++m)
        for (int n = 0; n < 4; ++n) {
            int row0 = bm0 + wr * 64 + m * 16 + g * 4;
            int col  = bn0 + wc * 64 + n * 16 + c;
            for (int j = 0; j < 4; ++j)
                out[(size_t)(row0 + j) * DA + col] = acc[m][n][j];
        }
}

// ---------------------------------------------------------------------------
extern "C" void kernel_launch(void* const* d_in, const int* in_sizes, int n_in,
                              void* d_out, int out_size, void* d_ws, size_t ws_size,
                              hipStream_t stream) {
    const float* queries = (const float*)d_in[0];
    const float* keys    = (const float*)d_in[1];
    const float* values  = (const float*)d_in[2];
    const float* Eq      = (const float*)d_in[3];
    const float* Ek      = (const float*)d_in[4];
    const float* Ev      = (const float*)d_in[5];
    const float* Wout    = (const float*)d_in[6];
    float* out = (float*)d_out;

    const size_t PROJ = (size_t)NH * SEQ * DKV;   // 8,388,608 elems
    const size_t TSZ  = (size_t)DA * DA;          // 4,194,304 elems
    u16* p  = (u16*)d_ws;
    u16* QH = p; p += PROJ;
    u16* QL = p; p += PROJ;
    u16* KH = p; p += PROJ;
    u16* KL = p; p += PROJ;
    u16* VT = p; p += PROJ;
    u16* AB = p; p += (size_t)SEQ * NH * DKV;
    u16* TH = p; p += TSZ;
    u16* TL = p; p += TSZ;

    dim3 tgE(DA / 32, DKV / 32, NH);   // E transposes
    dim3 tgW(DA / 32, DA / 32, 1);     // W transpose
    dim3 pg(SEQ / 128, NH);

    transpose_split_k<<<tgE, 256, 0, stream>>>(Eq, TH, TL, DA, DKV);
    proj_k<2><<<pg, 256, 0, stream>>>(queries, TH, TL, QH, QL);
    transpose_split_k<<<tgE, 256, 0, stream>>>(Ek, TH, TL, DA, DKV);
    proj_k<1><<<pg, 256, 0, stream>>>(keys, TH, TL, KH, KL);
    transpose_split_k<<<tgE, 256, 0, stream>>>(Ev, TH, nullptr, DA, DKV);
    proj_k<0><<<pg, 256, 0, stream>>>(values, TH, nullptr, VT, nullptr);
    transpose_split_k<<<tgW, 256, 0, stream>>>(Wout, TH, nullptr, DA, DA);
    attn_k<<<dim3(SEQ / 256 * NH), 512, 0, stream>>>(QH, QL, KH, KL, VT, AB);
    gemm_out_k<<<dim3(SEQ / 128, DA / 128), 256, 0, stream>>>(AB, TH, out);
}

// Round 11
// 590.926 us; speedup vs baseline: 1.0179x; 1.0179x over previous
//
#include <hip/hip_runtime.h>

typedef unsigned short u16;
typedef __attribute__((ext_vector_type(4)))  float  f32x4;
typedef __attribute__((ext_vector_type(16))) float  f32x16;
typedef __attribute__((ext_vector_type(4)))  float  float4v;
typedef __attribute__((ext_vector_type(4)))  unsigned short u16x4;
typedef __attribute__((ext_vector_type(8)))  unsigned short u16x8;
typedef __attribute__((ext_vector_type(8)))  short s16x8;
typedef __attribute__((ext_vector_type(4)))  unsigned int u32x4;

#define SEQ 4096
#define DA  2048
#define NH  16
#define DKV 128

__device__ __forceinline__ u16 f2bf(float f) {
    unsigned u = __builtin_bit_cast(unsigned, f);
    u += 0x7FFFu + ((u >> 16) & 1u);           // round-nearest-even
    return (u16)(u >> 16);
}
__device__ __forceinline__ float bf2f(u16 h) {
    return __builtin_bit_cast(float, (unsigned)h << 16);
}
__device__ __forceinline__ f32x4 mfma16(u16x8 a, u16x8 b, f32x4 c) {
    return __builtin_amdgcn_mfma_f32_16x16x32_bf16(
        __builtin_bit_cast(s16x8, a), __builtin_bit_cast(s16x8, b), c, 0, 0, 0);
}
__device__ __forceinline__ f32x16 mfma32(u16x8 a, u16x8 b, f32x16 c) {
    return __builtin_amdgcn_mfma_f32_32x32x16_bf16(
        __builtin_bit_cast(s16x8, a), __builtin_bit_cast(s16x8, b), c, 0, 0, 0);
}
__device__ __forceinline__ unsigned cvtpk(float lo, float hi) {
    unsigned r;
    asm("v_cvt_pk_bf16_f32 %0, %1, %2" : "=v"(r) : "v"(lo), "v"(hi));
    return r;
}
// direct-to-LDS 16B load: per-lane global src, wave-uniform LDS base (+lane*16)
__device__ __forceinline__ void gld16(const u16* g, u16* l) {
    __builtin_amdgcn_global_load_lds(
        (const __attribute__((address_space(1))) unsigned int*)g,
        (__attribute__((address_space(3))) unsigned int*)l, 16, 0, 0);
}
// swizzled LDS addressing, 128B rows: XOR row&7 into byte-bit-4..6
__device__ __forceinline__ char* ldsp(void* base, int row, int bcol, int rowbytes) {
    int off = row * rowbytes + bcol;
    off ^= (row & 7) << 4;
    return (char*)base + off;
}
// swizzled LDS addressing, 256B rows: XOR row&15 into byte-bit-4..7
__device__ __forceinline__ char* ldsp256(void* base, int row, int bcol) {
    int off = row * 256 + bcol;
    off ^= (row & 15) << 4;
    return (char*)base + off;
}

// ---------------------------------------------------------------------------
// Transpose + split-convert: in f32 [B][R][C] -> oh/ol bf16 [B][C][R]
// ---------------------------------------------------------------------------
__global__ void transpose_split_k(const float* __restrict__ in, u16* __restrict__ oh,
                                  u16* __restrict__ ol, int R, int C) {
    __shared__ float tile[32][33];
    int b  = blockIdx.z;
    int r0 = blockIdx.x * 32, c0 = blockIdx.y * 32;
    const float* src = in + (size_t)b * R * C;
    int t = threadIdx.x;
    {
        int cl = t & 31, r = t >> 5;
        for (int i = 0; i < 4; ++i)
            tile[r + 8 * i][cl] = src[(size_t)(r0 + r + 8 * i) * C + (c0 + cl)];
    }
    __syncthreads();
    int rl = t & 31, c = t >> 5;
    size_t obase = (size_t)b * R * C;
    for (int i = 0; i < 4; ++i) {
        int cw = c + 8 * i;
        float x = tile[rl][cw];
        u16 h = f2bf(x);
        size_t o = obase + (size_t)(c0 + cw) * R + (r0 + rl);
        oh[o] = h;
        if (ol) ol[o] = f2bf(x - bf2f(h));
    }
}

// ---------------------------------------------------------------------------
// Projection GEMM with T14 async-stage (R6-proven).
// MODE 0: V -> bf16 transposed VT[h][v][s] (hi only). MODE 1: K split. MODE 2: Q split*1/128.
// ---------------------------------------------------------------------------
template <int MODE>
__global__ void __launch_bounds__(256, 2) proj_k(const float* __restrict__ A,
                                                 const u16* __restrict__ BTh,
                                                 const u16* __restrict__ BTl,
                                                 u16* __restrict__ Oh,
                                                 u16* __restrict__ Ol) {
    __shared__ u16 sAh[128 * 64];
    __shared__ u16 sBh[128 * 64];
    __shared__ u16 sAl[MODE ? 128 * 64 : 8];
    __shared__ u16 sBl[MODE ? 128 * 64 : 8];

    int t = threadIdx.x;
    int h = blockIdx.y;
    int bm0 = blockIdx.x * 128;
    int lane = t & 63, w = t >> 6, wr = w >> 1, wc = w & 1;
    int g = lane >> 4, c = lane & 15;

    f32x4 acc[4][4] = {};

    float4v pA[8];
    u16x8   pBh[4], pBl[4];

    auto prefetch = [&](int k0) {
#pragma unroll
        for (int i = 0; i < 8; ++i) {
            int idx = t + i * 256;
            int row = idx >> 4, c4 = idx & 15;
            pA[i] = *(const float4v*)(A + (size_t)(bm0 + row) * DA + k0 + c4 * 4);
        }
#pragma unroll
        for (int i = 0; i < 4; ++i) {
            int idx = t + i * 256;
            int row = idx >> 3, c8 = idx & 7;
            size_t gb = ((size_t)h * 128 + row) * DA + k0 + c8 * 8;
            pBh[i] = *(const u16x8*)(BTh + gb);
            if (MODE) pBl[i] = *(const u16x8*)(BTl + gb);
        }
    };
    auto write_lds = [&]() {
#pragma unroll
        for (int i = 0; i < 8; ++i) {
            int idx = t + i * 256;
            int row = idx >> 4, c4 = idx & 15;
            u16x4 hv, lv;
#pragma unroll
            for (int j = 0; j < 4; ++j) {
                u16 hh = f2bf(pA[i][j]);
                hv[j] = hh;
                lv[j] = f2bf(pA[i][j] - bf2f(hh));
            }
            *(u16x4*)ldsp(sAh, row, c4 * 8, 128) = hv;
            if (MODE) *(u16x4*)ldsp(sAl, row, c4 * 8, 128) = lv;
        }
#pragma unroll
        for (int i = 0; i < 4; ++i) {
            int idx = t + i * 256;
            int row = idx >> 3, c8 = idx & 7;
            *(u16x8*)ldsp(sBh, row, c8 * 16, 128) = pBh[i];
            if (MODE) *(u16x8*)ldsp(sBl, row, c8 * 16, 128) = pBl[i];
        }
    };

    prefetch(0);
    for (int k0 = 0; k0 < DA; k0 += 64) {
        __syncthreads();
        write_lds();
        __syncthreads();
        int nxt = (k0 + 64 < DA) ? k0 + 64 : 0;
        prefetch(nxt);

        for (int kc = 0; kc < 2; ++kc) {
            int kb = (kc * 32 + g * 8) * 2;
            u16x8 ah[4], al[4], bh[4], bl[4];
            for (int m = 0; m < 4; ++m) {
                int row = wr * 64 + m * 16 + c;
                ah[m] = *(u16x8*)ldsp(sAh, row, kb, 128);
                if (MODE) al[m] = *(u16x8*)ldsp(sAl, row, kb, 128);
            }
            for (int n = 0; n < 4; ++n) {
                int row = wc * 64 + n * 16 + c;
                bh[n] = *(u16x8*)ldsp(sBh, row, kb, 128);
                if (MODE) bl[n] = *(u16x8*)ldsp(sBl, row, kb, 128);
            }
            for (int m = 0; m < 4; ++m)
                for (int n = 0; n < 4; ++n) {
                    acc[m][n] = mfma16(ah[m], bh[n], acc[m][n]);
                    if (MODE) {
                        acc[m][n] = mfma16(ah[m], bl[n], acc[m][n]);
                        acc[m][n] = mfma16(al[m], bh[n], acc[m][n]);
                    }
                }
        }
    }

    const float scale = (MODE == 2) ? (1.0f / 128.0f) : 1.0f;
    for (int m = 0; m < 4; ++m)
        for (int n = 0; n < 4; ++n) {
            int col  = wc * 64 + n * 16 + c;
            int row0 = bm0 + wr * 64 + m * 16 + g * 4;
            if (MODE == 0) {
                u16x4 pv;
                for (int j = 0; j < 4; ++j) pv[j] = f2bf(acc[m][n][j]);
                *(u16x4*)(Oh + ((size_t)h * DKV + col) * SEQ + row0) = pv;
            } else {
                for (int j = 0; j < 4; ++j) {
                    float v = acc[m][n][j] * scale;
                    u16 hh = f2bf(v);
                    size_t o = ((size_t)h * SEQ + row0 + j) * DKV + col;
                    Oh[o] = hh;
                    Ol[o] = f2bf(v - bf2f(hh));
                }
            }
        }
}

// ---------------------------------------------------------------------------
// Flash attention — exact R6 kernel (measured 265.7 µs, absmax 64):
// 32x32x16 MFMA, swapped QK^T, in-register softmax, cvt_pk + __shfl_xor(32)
// P-conversion, gld16 staging (inverse-swizzled sources), double-buffered LDS
// (single barrier/iter), T13 defer-rescale, XCD-aware grid decode.
// 8 waves x 32 q = 256 q-rows/block.
// ---------------------------------------------------------------------------
__global__ void __launch_bounds__(512, 1) attn_k(const u16* __restrict__ QH,
                                                 const u16* __restrict__ QL,
                                                 const u16* __restrict__ KH,
                                                 const u16* __restrict__ KL,
                                                 const u16* __restrict__ VT,
                                                 u16* __restrict__ Abuf) {
    __shared__ u16 sKh[2][64 * 128];
    __shared__ u16 sKl[2][64 * 128];
    __shared__ u16 sV [2][64 * 128];   // [64 rows][256B]: row r, half p = vdim p*64+r

    int t = threadIdx.x, lane = t & 63, w = t >> 6;   // w in 0..7
    int bid = blockIdx.x;
    int h  = (bid & 7) + 8 * ((bid >> 3) & 1);        // XCD x serves heads {x, x+8}
    int q0 = (bid >> 4) * 256;
    int c = lane & 31, hi = lane >> 5;
    int qrow = q0 + w * 32 + c;

    // Q fragments (B-operand layout): lane holds Q[qrow][dc*16 + hi*8 .. +7]
    u16x8 qh[8], ql[8];
    {
        size_t base = ((size_t)h * SEQ + qrow) * DKV + hi * 8;
#pragma unroll
        for (int dc = 0; dc < 8; ++dc) {
            qh[dc] = *(const u16x8*)(QH + base + dc * 16);
            ql[dc] = *(const u16x8*)(QL + base + dc * 16);
        }
    }

    f32x16 o[4] = {};
    float mrun = -3e38f, lrun = 0.f;

    const size_t kroot = (size_t)h * SEQ * DKV;
    const size_t vroot = (size_t)h * DKV * SEQ;

    auto stage = [&](int kv, int b) {
        const u16* khp = KH + kroot + (size_t)kv * DKV;
        const u16* klp = KL + kroot + (size_t)kv * DKV;
        const u16* vtp = VT + vroot + kv;
#pragma unroll
        for (int j = 0; j < 2; ++j) {
            int ci = w * 2 + j;                      // 1KB chunk index (0..15)
            int rK = ci * 4 + (lane >> 4);           // LDS row 0..63
            int cK = (lane & 15) ^ (rK & 15);        // inverse-swizzled granule col
            gld16(khp + rK * DKV + cK * 8, &sKh[b][ci * 512]);
            gld16(klp + rK * DKV + cK * 8, &sKl[b][ci * 512]);
            int vd = ((cK >> 3) << 6) + rK;          // vdim for V gather
            gld16(vtp + (size_t)vd * SEQ + (cK & 7) * 8, &sV[b][ci * 512]);
        }
    };

    stage(0, 0);
    const int NT = SEQ / 64;
    for (int it = 0; it < NT; ++it) {
        int b = it & 1;
        __syncthreads();               // drains own stage(it) loads, syncs all waves
        if (it + 1 < NT) stage((it + 1) * 64, b ^ 1);   // in flight under compute

        // S^T = K * Q^T : s[kt] holds S[kv=(r&3)+8*(r>>2)+4*hi + 32*kt][q=c]
        f32x16 s[2] = {};
        __builtin_amdgcn_s_setprio(1);
#pragma unroll
        for (int kt = 0; kt < 2; ++kt) {
#pragma unroll
            for (int dc = 0; dc < 8; ++dc) {
                u16x8 kh = *(u16x8*)ldsp256(sKh[b], kt * 32 + c, dc * 32 + hi * 16);
                u16x8 kl = *(u16x8*)ldsp256(sKl[b], kt * 32 + c, dc * 32 + hi * 16);
                s[kt] = mfma32(kh, qh[dc], s[kt]);
                s[kt] = mfma32(kl, qh[dc], s[kt]);
                s[kt] = mfma32(kh, ql[dc], s[kt]);
            }
        }
        __builtin_amdgcn_s_setprio(0);

        // online softmax with T13 defer-rescale (THR=8)
        float vmax = s[0][0];
#pragma unroll
        for (int r = 1; r < 16; ++r) vmax = fmaxf(vmax, s[0][r]);
#pragma unroll
        for (int r = 0; r < 16; ++r) vmax = fmaxf(vmax, s[1][r]);
        vmax = fmaxf(vmax, __shfl_xor(vmax, 32));
        if (!__all(vmax <= mrun + 8.0f)) {
            float mnew = fmaxf(mrun, vmax);
            float corr = __expf(mrun - mnew);
            mrun = mnew;
            lrun *= corr;
#pragma unroll
            for (int vt = 0; vt < 4; ++vt)
#pragma unroll
                for (int r = 0; r < 16; ++r) o[vt][r] *= corr;
        }
        float rs = 0.f;
#pragma unroll
        for (int kt = 0; kt < 2; ++kt)
#pragma unroll
            for (int r = 0; r < 16; ++r) {
                float p = __expf(s[kt][r] - mrun);
                s[kt][r] = p;
                rs += p;
            }
        rs += __shfl_xor(rs, 32);
        lrun += rs;

        // P -> B-frag (in-register) and PV: O^T += V^T · P^T
#pragma unroll
        for (int kt = 0; kt < 2; ++kt) {
            unsigned wv[8], xw[8];
#pragma unroll
            for (int i = 0; i < 8; ++i) wv[i] = cvtpk(s[kt][2 * i], s[kt][2 * i + 1]);
#pragma unroll
            for (int i = 0; i < 8; ++i) xw[i] = (unsigned)__shfl_xor((int)wv[i], 32);
            __builtin_amdgcn_s_setprio(1);
#pragma unroll
            for (int kc = 0; kc < 2; ++kc) {
                u32x4 pw;
                pw[0] = hi ? xw[4 * kc + 2] : wv[4 * kc + 0];
                pw[1] = hi ? xw[4 * kc + 3] : wv[4 * kc + 1];
                pw[2] = hi ? wv[4 * kc + 2] : xw[4 * kc + 0];
                pw[3] = hi ? wv[4 * kc + 3] : xw[4 * kc + 1];
                u16x8 pf = __builtin_bit_cast(u16x8, pw);
#pragma unroll
                for (int vt = 0; vt < 4; ++vt) {
                    int v = vt * 32 + c;
                    u16x8 vf = *(u16x8*)ldsp256(sV[b], v & 63,
                                                ((v >> 6) << 7) + kt * 64 + kc * 32 + hi * 16);
                    o[vt] = mfma32(vf, pf, o[vt]);
                }
            }
            __builtin_amdgcn_s_setprio(0);
        }
    }

    float inv = 1.0f / lrun;
#pragma unroll
    for (int vt = 0; vt < 4; ++vt)
#pragma unroll
        for (int rg = 0; rg < 4; ++rg) {
            u16x4 pv;
#pragma unroll
            for (int j = 0; j < 4; ++j) pv[j] = f2bf(o[vt][rg * 4 + j] * inv);
            *(u16x4*)(Abuf + (size_t)qrow * (NH * DKV) + h * DKV + vt * 32 + rg * 8 + hi * 4) = pv;
        }
}

// ---------------------------------------------------------------------------
// Final GEMM (T14, R6-proven): out f32 = Abuf bf16 @ W^T
// ---------------------------------------------------------------------------
__global__ void __launch_bounds__(256, 2) gemm_out_k(const u16* __restrict__ Abuf,
                                                     const u16* __restrict__ WT,
                                                     float* __restrict__ out) {
    __shared__ u16 sA[128 * 64];
    __shared__ u16 sB[128 * 64];
    int t = threadIdx.x, lane = t & 63, w = t >> 6, wr = w >> 1, wc = w & 1;
    int g = lane >> 4, c = lane & 15;
    int bm0 = blockIdx.x * 128, bn0 = blockIdx.y * 128;
    f32x4 acc[4][4] = {};

    u16x8 pA[4], pB[4];
    auto prefetch = [&](int k0) {
#pragma unroll
        for (int i = 0; i < 4; ++i) {
            int idx = t + i * 256, row = idx >> 3, c8 = idx & 7;
            pA[i] = *(const u16x8*)(Abuf + (size_t)(bm0 + row) * DA + k0 + c8 * 8);
            pB[i] = *(const u16x8*)(WT + (size_t)(bn0 + row) * DA + k0 + c8 * 8);
        }
    };
    auto write_lds = [&]() {
#pragma unroll
        for (int i = 0; i < 4; ++i) {
            int idx = t + i * 256, row = idx >> 3, c8 = idx & 7;
            *(u16x8*)ldsp(sA, row, c8 * 16, 128) = pA[i];
            *(u16x8*)ldsp(sB, row, c8 * 16, 128) = pB[i];
        }
    };

    prefetch(0);
    for (int k0 = 0; k0 < DA; k0 += 64) {
        __syncthreads();
        write_lds();
        __syncthreads();
        int nxt = (k0 + 64 < DA) ? k0 + 64 : 0;
        prefetch(nxt);

        for (int kc = 0; kc < 2; ++kc) {
            int kb = (kc * 32 + g * 8) * 2;
            u16x8 af[4], bfq[4];
            for (int m = 0; m < 4; ++m) af[m]  = *(u16x8*)ldsp(sA, wr * 64 + m * 16 + c, kb, 128);
            for (int n = 0; n < 4; ++n) bfq[n] = *(u16x8*)ldsp(sB, wc * 64 + n * 16 + c, kb, 128);
            for (int m = 0; m < 4; ++m)
                for (int n = 0; n < 4; ++n)
                    acc[m][n] = mfma16(af[m], bfq[n], acc[m][n]);
        }
    }
    for (int m = 0; m < 4; ++m)
        for (int n = 0; n < 4; ++n) {
            int row0 = bm0 + wr * 64 + m * 16 + g * 4;
            int col  = bn0 + wc * 64 + n * 16 + c;
            for (int j = 0; j < 4; ++j)
                out[(size_t)(row0 + j) * DA + col] = acc[m][n][j];
        }
}

// ---------------------------------------------------------------------------
extern "C" void kernel_launch(void* const* d_in, const int* in_sizes, int n_in,
                              void* d_out, int out_size, void* d_ws, size_t ws_size,
                              hipStream_t stream) {
    const float* queries = (const float*)d_in[0];
    const float* keys    = (const float*)d_in[1];
    const float* values  = (const float*)d_in[2];
    const float* Eq      = (const float*)d_in[3];
    const float* Ek      = (const float*)d_in[4];
    const float* Ev      = (const float*)d_in[5];
    const float* Wout    = (const float*)d_in[6];
    float* out = (float*)d_out;

    const size_t PROJ = (size_t)NH * SEQ * DKV;   // 8,388,608 elems
    const size_t TSZ  = (size_t)DA * DA;          // 4,194,304 elems
    u16* p  = (u16*)d_ws;
    u16* QH = p; p += PROJ;
    u16* QL = p; p += PROJ;
    u16* KH = p; p += PROJ;
    u16* KL = p; p += PROJ;
    u16* VT = p; p += PROJ;
    u16* AB = p; p += (size_t)SEQ * NH * DKV;
    u16* TH = p; p += TSZ;
    u16* TL = p; p += TSZ;

    dim3 tgE(DA / 32, DKV / 32, NH);   // E transposes
    dim3 tgW(DA / 32, DA / 32, 1);     // W transpose
    dim3 pg(SEQ / 128, NH);

    transpose_split_k<<<tgE, 256, 0, stream>>>(Eq, TH, TL, DA, DKV);
    proj_k<2><<<pg, 256, 0, stream>>>(queries, TH, TL, QH, QL);
    transpose_split_k<<<tgE, 256, 0, stream>>>(Ek, TH, TL, DA, DKV);
    proj_k<1><<<pg, 256, 0, stream>>>(keys, TH, TL, KH, KL);
    transpose_split_k<<<tgE, 256, 0, stream>>>(Ev, TH, nullptr, DA, DKV);
    proj_k<0><<<pg, 256, 0, stream>>>(values, TH, nullptr, VT, nullptr);
    transpose_split_k<<<tgW, 256, 0, stream>>>(Wout, TH, nullptr, DA, DA);
    attn_k<<<dim3(SEQ / 256 * NH), 512, 0, stream>>>(QH, QL, KH, KL, VT, AB);
    gemm_out_k<<<dim3(SEQ / 128, DA / 128), 256, 0, stream>>>(AB, TH, out);
}

// Round 12
// 573.811 us; speedup vs baseline: 1.0482x; 1.0298x over previous
//
#include <hip/hip_runtime.h>

typedef unsigned short u16;
typedef __attribute__((ext_vector_type(4)))  float  f32x4;
typedef __attribute__((ext_vector_type(16))) float  f32x16;
typedef __attribute__((ext_vector_type(4)))  float  float4v;
typedef __attribute__((ext_vector_type(4)))  unsigned short u16x4;
typedef __attribute__((ext_vector_type(8)))  unsigned short u16x8;
typedef __attribute__((ext_vector_type(8)))  short s16x8;
typedef __attribute__((ext_vector_type(4)))  unsigned int u32x4;

#define SEQ 4096
#define DA  2048
#define NH  16
#define DKV 128

__device__ __forceinline__ u16 f2bf(float f) {
    unsigned u = __builtin_bit_cast(unsigned, f);
    u += 0x7FFFu + ((u >> 16) & 1u);           // round-nearest-even
    return (u16)(u >> 16);
}
__device__ __forceinline__ float bf2f(u16 h) {
    return __builtin_bit_cast(float, (unsigned)h << 16);
}
__device__ __forceinline__ f32x4 mfma16(u16x8 a, u16x8 b, f32x4 c) {
    return __builtin_amdgcn_mfma_f32_16x16x32_bf16(
        __builtin_bit_cast(s16x8, a), __builtin_bit_cast(s16x8, b), c, 0, 0, 0);
}
__device__ __forceinline__ f32x16 mfma32(u16x8 a, u16x8 b, f32x16 c) {
    return __builtin_amdgcn_mfma_f32_32x32x16_bf16(
        __builtin_bit_cast(s16x8, a), __builtin_bit_cast(s16x8, b), c, 0, 0, 0);
}
__device__ __forceinline__ unsigned cvtpk(float lo, float hi) {
    unsigned r;
    asm("v_cvt_pk_bf16_f32 %0, %1, %2" : "=v"(r) : "v"(lo), "v"(hi));
    return r;
}
// direct-to-LDS 16B load: per-lane global src, wave-uniform LDS base (+lane*16)
__device__ __forceinline__ void gld16(const u16* g, u16* l) {
    __builtin_amdgcn_global_load_lds(
        (const __attribute__((address_space(1))) unsigned int*)g,
        (__attribute__((address_space(3))) unsigned int*)l, 16, 0, 0);
}
// swizzled LDS addressing, 128B rows: XOR row&7 into byte-bit-4..6
__device__ __forceinline__ char* ldsp(void* base, int row, int bcol, int rowbytes) {
    int off = row * rowbytes + bcol;
    off ^= (row & 7) << 4;
    return (char*)base + off;
}
// swizzled LDS addressing, 256B rows: XOR row&15 into byte-bit-4..7
__device__ __forceinline__ char* ldsp256(void* base, int row, int bcol) {
    int off = row * 256 + bcol;
    off ^= (row & 15) << 4;
    return (char*)base + off;
}

// ---------------------------------------------------------------------------
// Transpose + split-convert: in f32 [B][R][C] -> oh/ol bf16 [B][C][R]
// ---------------------------------------------------------------------------
__global__ void transpose_split_k(const float* __restrict__ in, u16* __restrict__ oh,
                                  u16* __restrict__ ol, int R, int C) {
    __shared__ float tile[32][33];
    int b  = blockIdx.z;
    int r0 = blockIdx.x * 32, c0 = blockIdx.y * 32;
    const float* src = in + (size_t)b * R * C;
    int t = threadIdx.x;
    {
        int cl = t & 31, r = t >> 5;
        for (int i = 0; i < 4; ++i)
            tile[r + 8 * i][cl] = src[(size_t)(r0 + r + 8 * i) * C + (c0 + cl)];
    }
    __syncthreads();
    int rl = t & 31, c = t >> 5;
    size_t obase = (size_t)b * R * C;
    for (int i = 0; i < 4; ++i) {
        int cw = c + 8 * i;
        float x = tile[rl][cw];
        u16 h = f2bf(x);
        size_t o = obase + (size_t)(c0 + cw) * R + (r0 + rl);
        oh[o] = h;
        if (ol) ol[o] = f2bf(x - bf2f(h));
    }
}

// ---------------------------------------------------------------------------
// Row-major split-convert: in f32 [n], scale -> oh (hi), ol (lo residual)
// ---------------------------------------------------------------------------
__global__ void split_cvt_k(const float* __restrict__ in, u16* __restrict__ oh,
                            u16* __restrict__ ol, float scale, int n) {
    int stride = gridDim.x * 256 * 4;
    for (int i = (blockIdx.x * 256 + threadIdx.x) * 4; i < n; i += stride) {
        float4v v = *(const float4v*)(in + i);
        u16x4 hv, lv;
#pragma unroll
        for (int j = 0; j < 4; ++j) {
            float x = v[j] * scale;
            u16 hh = f2bf(x);
            hv[j] = hh;
            lv[j] = f2bf(x - bf2f(hh));
        }
        *(u16x4*)(oh + i) = hv;
        if (ol) *(u16x4*)(ol + i) = lv;
    }
}

// ---------------------------------------------------------------------------
// Projection GEMM v2: pure-bf16 inputs, gld16 staging (inverse-swizzled src),
// m97 2-barrier structure, 2 blocks/CU. C[h][s][n] = sum_k A[s][k]*E[h][k][n].
// A: pre-split bf16 [SEQ][DA] (hi[,lo]). B: bf16 [h*128+n][DA] (hi[,lo]).
// MODE 0: V (1 chain) -> VT[h][v][s]. MODE 1: K (3 chains, split out).
// MODE 2: Q (3 chains, split out; input pre-scaled by 1/128).
// ---------------------------------------------------------------------------
template <int MODE>
__global__ void __launch_bounds__(256, 2) proj2_k(const u16* __restrict__ ASh,
                                                  const u16* __restrict__ ASl,
                                                  const u16* __restrict__ BTh,
                                                  const u16* __restrict__ BTl,
                                                  u16* __restrict__ Oh,
                                                  u16* __restrict__ Ol) {
    __shared__ u16 sAh[128 * 64];
    __shared__ u16 sBh[128 * 64];
    __shared__ u16 sAl[MODE ? 128 * 64 : 8];
    __shared__ u16 sBl[MODE ? 128 * 64 : 8];

    int t = threadIdx.x;
    int h = blockIdx.y;
    int bm0 = blockIdx.x * 128;
    int lane = t & 63, w = t >> 6, wr = w >> 1, wc = w & 1;
    int g = lane >> 4, c = lane & 15;

    // staging geometry: array = 128 rows x 128B; chunk = 1KB = 8 rows;
    // 16 chunks/array, 4 waves -> chunks w*4..w*4+3. lane: row_in_chunk=lane>>3,
    // source granule = (lane&7) ^ (lane>>3)  (inverse of read-side XOR swizzle).
    int rin = lane >> 3;
    int cg  = (lane & 7) ^ rin;

    f32x4 acc[4][4] = {};

    for (int k0 = 0; k0 < DA; k0 += 64) {
        __syncthreads();
#pragma unroll
        for (int j = 0; j < 4; ++j) {
            int chunk = w * 4 + j;
            int r = chunk * 8 + rin;
            size_t ga = (size_t)(bm0 + r) * DA + k0 + cg * 8;
            size_t gb = ((size_t)h * 128 + r) * DA + k0 + cg * 8;
            gld16(ASh + ga, &sAh[chunk * 512]);
            gld16(BTh + gb, &sBh[chunk * 512]);
            if (MODE) {
                gld16(ASl + ga, &sAl[chunk * 512]);
                gld16(BTl + gb, &sBl[chunk * 512]);
            }
        }
        __syncthreads();   // vmcnt(0) drained before barrier -> LDS ready

        for (int kc = 0; kc < 2; ++kc) {
            int kb = (kc * 32 + g * 8) * 2;
            u16x8 ah[4], al[4], bh[4], bl[4];
            for (int m = 0; m < 4; ++m) {
                int row = wr * 64 + m * 16 + c;
                ah[m] = *(u16x8*)ldsp(sAh, row, kb, 128);
                if (MODE) al[m] = *(u16x8*)ldsp(sAl, row, kb, 128);
            }
            for (int n = 0; n < 4; ++n) {
                int row = wc * 64 + n * 16 + c;
                bh[n] = *(u16x8*)ldsp(sBh, row, kb, 128);
                if (MODE) bl[n] = *(u16x8*)ldsp(sBl, row, kb, 128);
            }
            for (int m = 0; m < 4; ++m)
                for (int n = 0; n < 4; ++n) {
                    acc[m][n] = mfma16(ah[m], bh[n], acc[m][n]);
                    if (MODE) {
                        acc[m][n] = mfma16(ah[m], bl[n], acc[m][n]);
                        acc[m][n] = mfma16(al[m], bh[n], acc[m][n]);
                    }
                }
        }
    }

    for (int m = 0; m < 4; ++m)
        for (int n = 0; n < 4; ++n) {
            int col  = wc * 64 + n * 16 + c;
            int row0 = bm0 + wr * 64 + m * 16 + g * 4;
            if (MODE == 0) {
                u16x4 pv;
                for (int j = 0; j < 4; ++j) pv[j] = f2bf(acc[m][n][j]);
                *(u16x4*)(Oh + ((size_t)h * DKV + col) * SEQ + row0) = pv;
            } else {
                for (int j = 0; j < 4; ++j) {
                    float v = acc[m][n][j];
                    u16 hh = f2bf(v);
                    size_t o = ((size_t)h * SEQ + row0 + j) * DKV + col;
                    Oh[o] = hh;
                    Ol[o] = f2bf(v - bf2f(hh));
                }
            }
        }
}

// ---------------------------------------------------------------------------
// Flash attention — exact R6 kernel (measured 265.7 µs, absmax 64): untouched.
// ---------------------------------------------------------------------------
__global__ void __launch_bounds__(512, 1) attn_k(const u16* __restrict__ QH,
                                                 const u16* __restrict__ QL,
                                                 const u16* __restrict__ KH,
                                                 const u16* __restrict__ KL,
                                                 const u16* __restrict__ VT,
                                                 u16* __restrict__ Abuf) {
    __shared__ u16 sKh[2][64 * 128];
    __shared__ u16 sKl[2][64 * 128];
    __shared__ u16 sV [2][64 * 128];   // [64 rows][256B]: row r, half p = vdim p*64+r

    int t = threadIdx.x, lane = t & 63, w = t >> 6;   // w in 0..7
    int bid = blockIdx.x;
    int h  = (bid & 7) + 8 * ((bid >> 3) & 1);        // XCD x serves heads {x, x+8}
    int q0 = (bid >> 4) * 256;
    int c = lane & 31, hi = lane >> 5;
    int qrow = q0 + w * 32 + c;

    // Q fragments (B-operand layout): lane holds Q[qrow][dc*16 + hi*8 .. +7]
    u16x8 qh[8], ql[8];
    {
        size_t base = ((size_t)h * SEQ + qrow) * DKV + hi * 8;
#pragma unroll
        for (int dc = 0; dc < 8; ++dc) {
            qh[dc] = *(const u16x8*)(QH + base + dc * 16);
            ql[dc] = *(const u16x8*)(QL + base + dc * 16);
        }
    }

    f32x16 o[4] = {};
    float mrun = -3e38f, lrun = 0.f;

    const size_t kroot = (size_t)h * SEQ * DKV;
    const size_t vroot = (size_t)h * DKV * SEQ;

    auto stage = [&](int kv, int b) {
        const u16* khp = KH + kroot + (size_t)kv * DKV;
        const u16* klp = KL + kroot + (size_t)kv * DKV;
        const u16* vtp = VT + vroot + kv;
#pragma unroll
        for (int j = 0; j < 2; ++j) {
            int ci = w * 2 + j;                      // 1KB chunk index (0..15)
            int rK = ci * 4 + (lane >> 4);           // LDS row 0..63
            int cK = (lane & 15) ^ (rK & 15);        // inverse-swizzled granule col
            gld16(khp + rK * DKV + cK * 8, &sKh[b][ci * 512]);
            gld16(klp + rK * DKV + cK * 8, &sKl[b][ci * 512]);
            int vd = ((cK >> 3) << 6) + rK;          // vdim for V gather
            gld16(vtp + (size_t)vd * SEQ + (cK & 7) * 8, &sV[b][ci * 512]);
        }
    };

    stage(0, 0);
    const int NT = SEQ / 64;
    for (int it = 0; it < NT; ++it) {
        int b = it & 1;
        __syncthreads();               // drains own stage(it) loads, syncs all waves
        if (it + 1 < NT) stage((it + 1) * 64, b ^ 1);   // in flight under compute

        // S^T = K * Q^T : s[kt] holds S[kv=(r&3)+8*(r>>2)+4*hi + 32*kt][q=c]
        f32x16 s[2] = {};
        __builtin_amdgcn_s_setprio(1);
#pragma unroll
        for (int kt = 0; kt < 2; ++kt) {
#pragma unroll
            for (int dc = 0; dc < 8; ++dc) {
                u16x8 kh = *(u16x8*)ldsp256(sKh[b], kt * 32 + c, dc * 32 + hi * 16);
                u16x8 kl = *(u16x8*)ldsp256(sKl[b], kt * 32 + c, dc * 32 + hi * 16);
                s[kt] = mfma32(kh, qh[dc], s[kt]);
                s[kt] = mfma32(kl, qh[dc], s[kt]);
                s[kt] = mfma32(kh, ql[dc], s[kt]);
            }
        }
        __builtin_amdgcn_s_setprio(0);

        // online softmax with T13 defer-rescale (THR=8)
        float vmax = s[0][0];
#pragma unroll
        for (int r = 1; r < 16; ++r) vmax = fmaxf(vmax, s[0][r]);
#pragma unroll
        for (int r = 0; r < 16; ++r) vmax = fmaxf(vmax, s[1][r]);
        vmax = fmaxf(vmax, __shfl_xor(vmax, 32));
        if (!__all(vmax <= mrun + 8.0f)) {
            float mnew = fmaxf(mrun, vmax);
            float corr = __expf(mrun - mnew);
            mrun = mnew;
            lrun *= corr;
#pragma unroll
            for (int vt = 0; vt < 4; ++vt)
#pragma unroll
                for (int r = 0; r < 16; ++r) o[vt][r] *= corr;
        }
        float rs = 0.f;
#pragma unroll
        for (int kt = 0; kt < 2; ++kt)
#pragma unroll
            for (int r = 0; r < 16; ++r) {
                float p = __expf(s[kt][r] - mrun);
                s[kt][r] = p;
                rs += p;
            }
        rs += __shfl_xor(rs, 32);
        lrun += rs;

        // P -> B-frag (in-register) and PV: O^T += V^T · P^T
#pragma unroll
        for (int kt = 0; kt < 2; ++kt) {
            unsigned wv[8], xw[8];
#pragma unroll
            for (int i = 0; i < 8; ++i) wv[i] = cvtpk(s[kt][2 * i], s[kt][2 * i + 1]);
#pragma unroll
            for (int i = 0; i < 8; ++i) xw[i] = (unsigned)__shfl_xor((int)wv[i], 32);
            __builtin_amdgcn_s_setprio(1);
#pragma unroll
            for (int kc = 0; kc < 2; ++kc) {
                u32x4 pw;
                pw[0] = hi ? xw[4 * kc + 2] : wv[4 * kc + 0];
                pw[1] = hi ? xw[4 * kc + 3] : wv[4 * kc + 1];
                pw[2] = hi ? wv[4 * kc + 2] : xw[4 * kc + 0];
                pw[3] = hi ? wv[4 * kc + 3] : xw[4 * kc + 1];
                u16x8 pf = __builtin_bit_cast(u16x8, pw);
#pragma unroll
                for (int vt = 0; vt < 4; ++vt) {
                    int v = vt * 32 + c;
                    u16x8 vf = *(u16x8*)ldsp256(sV[b], v & 63,
                                                ((v >> 6) << 7) + kt * 64 + kc * 32 + hi * 16);
                    o[vt] = mfma32(vf, pf, o[vt]);
                }
            }
            __builtin_amdgcn_s_setprio(0);
        }
    }

    float inv = 1.0f / lrun;
#pragma unroll
    for (int vt = 0; vt < 4; ++vt)
#pragma unroll
        for (int rg = 0; rg < 4; ++rg) {
            u16x4 pv;
#pragma unroll
            for (int j = 0; j < 4; ++j) pv[j] = f2bf(o[vt][rg * 4 + j] * inv);
            *(u16x4*)(Abuf + (size_t)qrow * (NH * DKV) + h * DKV + vt * 32 + rg * 8 + hi * 4) = pv;
        }
}

// ---------------------------------------------------------------------------
// Final GEMM v2 (gld16 staging, m97 structure): out f32 = Abuf bf16 @ W^T
// ---------------------------------------------------------------------------
__global__ void __launch_bounds__(256, 2) gemm_out_k(const u16* __restrict__ Abuf,
                                                     const u16* __restrict__ WT,
                                                     float* __restrict__ out) {
    __shared__ u16 sA[128 * 64];
    __shared__ u16 sB[128 * 64];
    int t = threadIdx.x, lane = t & 63, w = t >> 6, wr = w >> 1, wc = w & 1;
    int g = lane >> 4, c = lane & 15;
    int bm0 = blockIdx.x * 128, bn0 = blockIdx.y * 128;
    int rin = lane >> 3;
    int cg  = (lane & 7) ^ rin;
    f32x4 acc[4][4] = {};

    for (int k0 = 0; k0 < DA; k0 += 64) {
        __syncthreads();
#pragma unroll
        for (int j = 0; j < 4; ++j) {
            int chunk = w * 4 + j;
            int r = chunk * 8 + rin;
            gld16(Abuf + (size_t)(bm0 + r) * DA + k0 + cg * 8, &sA[chunk * 512]);
            gld16(WT   + (size_t)(bn0 + r) * DA + k0 + cg * 8, &sB[chunk * 512]);
        }
        __syncthreads();

        for (int kc = 0; kc < 2; ++kc) {
            int kb = (kc * 32 + g * 8) * 2;
            u16x8 af[4], bfq[4];
            for (int m = 0; m < 4; ++m) af[m]  = *(u16x8*)ldsp(sA, wr * 64 + m * 16 + c, kb, 128);
            for (int n = 0; n < 4; ++n) bfq[n] = *(u16x8*)ldsp(sB, wc * 64 + n * 16 + c, kb, 128);
            for (int m = 0; m < 4; ++m)
                for (int n = 0; n < 4; ++n)
                    acc[m][n] = mfma16(af[m], bfq[n], acc[m][n]);
        }
    }
    for (int m = 0; m < 4; ++m)
        for (int n = 0; n < 4; ++n) {
            int row0 = bm0 + wr * 64 + m * 16 + g * 4;
            int col  = bn0 + wc * 64 + n * 16 + c;
            for (int j = 0; j < 4; ++j)
                out[(size_t)(row0 + j) * DA + col] = acc[m][n][j];
        }
}

// ---------------------------------------------------------------------------
extern "C" void kernel_launch(void* const* d_in, const int* in_sizes, int n_in,
                              void* d_out, int out_size, void* d_ws, size_t ws_size,
                              hipStream_t stream) {
    const float* queries = (const float*)d_in[0];
    const float* keys    = (const float*)d_in[1];
    const float* values  = (const float*)d_in[2];
    const float* Eq      = (const float*)d_in[3];
    const float* Ek      = (const float*)d_in[4];
    const float* Ev      = (const float*)d_in[5];
    const float* Wout    = (const float*)d_in[6];
    float* out = (float*)d_out;

    const size_t PROJ = (size_t)NH * SEQ * DKV;   // 8,388,608 elems
    const size_t TSZ  = (size_t)DA * DA;          // 4,194,304 elems
    const size_t ASZ  = (size_t)SEQ * DA;         // 8,388,608 elems
    u16* p  = (u16*)d_ws;
    u16* QH = p; p += PROJ;
    u16* QL = p; p += PROJ;
    u16* KH = p; p += PROJ;
    u16* KL = p; p += PROJ;
    u16* VT = p; p += PROJ;
    u16* AB = p; p += (size_t)SEQ * NH * DKV;
    u16* TH = p; p += TSZ;
    u16* TL = p; p += TSZ;
    u16* Sh = p; p += ASZ;
    u16* Sl = p; p += ASZ;

    dim3 tgE(DA / 32, DKV / 32, NH);   // E transposes
    dim3 tgW(DA / 32, DA / 32, 1);     // W transpose
    dim3 pg(SEQ / 128, NH);
    const int NELEM = SEQ * DA;

    // Q chain (queries pre-scaled by 1/128 — power of 2, exact)
    transpose_split_k<<<tgE, 256, 0, stream>>>(Eq, TH, TL, DA, DKV);
    split_cvt_k<<<2048, 256, 0, stream>>>(queries, Sh, Sl, 1.0f / 128.0f, NELEM);
    proj2_k<2><<<pg, 256, 0, stream>>>(Sh, Sl, TH, TL, QH, QL);
    // K chain
    transpose_split_k<<<tgE, 256, 0, stream>>>(Ek, TH, TL, DA, DKV);
    split_cvt_k<<<2048, 256, 0, stream>>>(keys, Sh, Sl, 1.0f, NELEM);
    proj2_k<1><<<pg, 256, 0, stream>>>(Sh, Sl, TH, TL, KH, KL);
    // V chain (hi only)
    transpose_split_k<<<tgE, 256, 0, stream>>>(Ev, TH, nullptr, DA, DKV);
    split_cvt_k<<<2048, 256, 0, stream>>>(values, Sh, nullptr, 1.0f, NELEM);
    proj2_k<0><<<pg, 256, 0, stream>>>(Sh, nullptr, TH, nullptr, VT, nullptr);
    // W transpose (hi only)
    transpose_split_k<<<tgW, 256, 0, stream>>>(Wout, TH, nullptr, DA, DA);
    // attention
    attn_k<<<dim3(SEQ / 256 * NH), 512, 0, stream>>>(QH, QL, KH, KL, VT, AB);
    // output projection
    gemm_out_k<<<dim3(SEQ / 128, DA / 128), 256, 0, stream>>>(AB, TH, out);
}